// Round 6
// baseline (1721.555 us; speedup 1.0000x reference)
//
#include <hip/hip_runtime.h>
#include <hip/hip_bf16.h>

// SkipGRU: B=64, T=4096, F=128, U=128, P=16 -> 1024 chains of length 256.
// Round-4 monolithic structure, but TWO independent batches per WG:
// 32 WGs x 16 waves (1024 thr). Waves 0-7 run batch 2*bid, waves 8-15 run
// batch 2*bid+1 -> 4 waves/SIMD with two independent dependency streams,
// hiding the per-step latency chain (ds_read -> h-MFMA -> gate -> barrier).
// Per-wave: one 16-col u-slice of all three gates; weights + gates + h-state
// in registers; x-MFMAs for step l+1 pipelined into the h-MFMA shadow.

#define B_N 64
#define T_N 4096
#define F_N 128
#define U_N 128
#define P_N 16
#define L_N 256
#define NW 16
#define NT (NW * 64)   // 1024 threads

typedef _Float16 f16x8 __attribute__((ext_vector_type(8)));
typedef _Float16 f16x4 __attribute__((ext_vector_type(4)));
typedef float f32x4 __attribute__((ext_vector_type(4)));

__device__ __forceinline__ float sigmoidf_(float x) {
    return __builtin_amdgcn_rcpf(1.0f + __expf(-x));
}

// Position of logical k within a fragment-contiguous row:
// row[kt*32 + lg*8 + e] holds k = kt*32 + 16*(e>>2) + 4*lg + (e&3).
__device__ __forceinline__ int fpos(int k) {
    return ((k >> 5) << 5) + (((k >> 2) & 3) << 3) + (((k >> 4) & 1) << 2) + (k & 3);
}

// barrier with LDS-only drain; global loads/stores stay in flight
#define BAR() do { \
    asm volatile("s_waitcnt lgkmcnt(0)" ::: "memory"); \
    __builtin_amdgcn_s_barrier(); \
    __builtin_amdgcn_sched_barrier(0); \
} while (0)

struct Acc { f32x4 z, r, xh, hh; };

__global__ __launch_bounds__(NT, 4) void skipgru_kernel(
    const float* __restrict__ xg, const float* __restrict__ Wk,
    const float* __restrict__ Wr, const float* __restrict__ bias,
    float* __restrict__ out)
{
    // Fragment-contiguous A operands per batch, padded rows (264 B) for banks.
    __shared__ __align__(16) _Float16 A_x[2][2][16][132];  // [bat][buf][m][k]
    __shared__ __align__(16) _Float16 A_h[2][2][16][132];

    const int tid  = threadIdx.x;
    const int lane = tid & 63;
    const int wave = tid >> 6;
    const int bat  = wave >> 3;      // which of the two batches in this WG
    const int ws   = wave & 7;       // wave-slice within the batch
    const int ln   = lane & 15;      // A-row / C-col index
    const int lg   = lane >> 4;      // k-group (A/B), row-group (C/D)
    const int u    = ws * 16 + ln;   // this lane's output column
    const int m0   = lg * 4;         // this lane's C/D row base
    const int b    = blockIdx.x * 2 + bat;
    const int hcol = fpos(u);        // A_h transpose-write column

    // --- per-lane bias scalars (z/r pre-summed input+recurrent)
    const float bz  = bias[u]       + bias[384 + u];
    const float br  = bias[128 + u] + bias[384 + 128 + u];
    const float bxh = bias[256 + u];
    const float brh = bias[384 + 256 + u];

    // --- weight fragments: 6 B-frag sets (z/r/h x Wk/Wr), k-map = fpos inverse
    f16x8 wzk[4], wzr[4], wrk[4], wrr[4], whk[4], whr[4];
    #pragma unroll
    for (int kt = 0; kt < 4; ++kt) {
        #pragma unroll
        for (int e = 0; e < 8; ++e) {
            int k = kt * 32 + ((e >> 2) << 4) + (lg << 2) + (e & 3);
            const float* wkp = Wk + (size_t)k * 384;
            const float* wrp = Wr + (size_t)k * 384;
            wzk[kt][e] = (_Float16)wkp[u];
            wzr[kt][e] = (_Float16)wrp[u];
            wrk[kt][e] = (_Float16)wkp[128 + u];
            wrr[kt][e] = (_Float16)wrp[128 + u];
            whk[kt][e] = (_Float16)wkp[256 + u];
            whr[kt][e] = (_Float16)wrp[256 + u];
        }
    }

    // --- zero A_h[bat][0] (h(-P) = 0): each 512-thread half does its batch
    const int lt = tid & 511;        // thread id within the batch half
    for (int q = lt; q < 16 * 132; q += 512)
        ((_Float16*)A_h[bat][0])[q] = (_Float16)0;

    // --- x staging map: half-local thread -> (row sm, col-quad sc)
    const int sm = lt & 15, sc = (lt >> 4) << 2;
    const int scp = fpos(sc);        // sc%4==0 -> 4 consecutive frag slots
    const float* xb = xg + (size_t)b * T_N * F_N;
    {
        float4 x0 = *(const float4*)(xb + (size_t)sm * F_N + sc);
        float4 x1 = *(const float4*)(xb + (size_t)(P_N + sm) * F_N + sc);
        f16x4 v0 = {(_Float16)x0.x, (_Float16)x0.y, (_Float16)x0.z, (_Float16)x0.w};
        f16x4 v1 = {(_Float16)x1.x, (_Float16)x1.y, (_Float16)x1.z, (_Float16)x1.w};
        *(f16x4*)&A_x[bat][0][sm][scp] = v0;
        *(f16x4*)&A_x[bat][1][sm][scp] = v1;
    }
    float4 xsB = *(const float4*)(xb + (size_t)(2 * P_N + sm) * F_N + sc);  // L(2)
    float4 xsA = *(const float4*)(xb + (size_t)(3 * P_N + sm) * F_N + sc);  // L(3)

    f32x4 hreg = {0.f, 0.f, 0.f, 0.f};
    float* op = out + ((size_t)b * T_N + m0) * U_N + u;
    __syncthreads();   // one-time full drain (staging + A_h zero visible)

    // --- prologue: x-part of step 0 into acc set P
    Acc P, Q;
    {
        f16x8 axf[4];
        #pragma unroll
        for (int kt = 0; kt < 4; ++kt)
            axf[kt] = *(const f16x8*)&A_x[bat][0][ln][kt * 32 + lg * 8];
        P.z  = {bz, bz, bz, bz};
        P.r  = {br, br, br, br};
        P.xh = {bxh, bxh, bxh, bxh};
        P.hh = {brh, brh, brh, brh};
        #pragma unroll
        for (int kt = 0; kt < 4; ++kt) {
            P.z  = __builtin_amdgcn_mfma_f32_16x16x32_f16(axf[kt], wzk[kt], P.z, 0, 0, 0);
            P.r  = __builtin_amdgcn_mfma_f32_16x16x32_f16(axf[kt], wrk[kt], P.r, 0, 0, 0);
            P.xh = __builtin_amdgcn_mfma_f32_16x16x32_f16(axf[kt], whk[kt], P.xh, 0, 0, 0);
        }
    }

    auto step = [&](int l, float4& xs, Acc& cur, Acc& nxt) {
        const int rbuf = l & 1, wbuf = (l + 1) & 1;
        // ---- critical path: A_h fragments -> 12 h-MFMAs into cur
        f16x8 ahf[4];
        #pragma unroll
        for (int kt = 0; kt < 4; ++kt)
            ahf[kt] = *(const f16x8*)&A_h[bat][rbuf][ln][kt * 32 + lg * 8];
        #pragma unroll
        for (int kt = 0; kt < 4; ++kt) {
            cur.z  = __builtin_amdgcn_mfma_f32_16x16x32_f16(ahf[kt], wzr[kt], cur.z, 0, 0, 0);
            cur.r  = __builtin_amdgcn_mfma_f32_16x16x32_f16(ahf[kt], wrr[kt], cur.r, 0, 0, 0);
            cur.hh = __builtin_amdgcn_mfma_f32_16x16x32_f16(ahf[kt], whr[kt], cur.hh, 0, 0, 0);
        }
        // ---- independent: x-part of step l+1 into nxt (fills idle slots)
        if (l + 1 < L_N) {
            f16x8 axf[4];
            #pragma unroll
            for (int kt = 0; kt < 4; ++kt)
                axf[kt] = *(const f16x8*)&A_x[bat][wbuf][ln][kt * 32 + lg * 8];
            nxt.z  = {bz, bz, bz, bz};
            nxt.r  = {br, br, br, br};
            nxt.xh = {bxh, bxh, bxh, bxh};
            nxt.hh = {brh, brh, brh, brh};
            #pragma unroll
            for (int kt = 0; kt < 4; ++kt) {
                nxt.z  = __builtin_amdgcn_mfma_f32_16x16x32_f16(axf[kt], wzk[kt], nxt.z, 0, 0, 0);
                nxt.r  = __builtin_amdgcn_mfma_f32_16x16x32_f16(axf[kt], wrk[kt], nxt.r, 0, 0, 0);
                nxt.xh = __builtin_amdgcn_mfma_f32_16x16x32_f16(axf[kt], whk[kt], nxt.xh, 0, 0, 0);
            }
        }
        // ---- gate fully in-register; h never leaves the lane
        #pragma unroll
        for (int e = 0; e < 4; ++e) {
            float z = sigmoidf_(cur.z[e]);
            float r = sigmoidf_(cur.r[e]);
            float c = fmaxf(0.f, fmaf(r, cur.hh[e], cur.xh[e]));
            float hn = fmaf(z, hreg[e] - c, c);
            hreg[e] = hn;
            A_h[bat][wbuf][m0 + e][hcol] = (_Float16)hn;  // transpose write (b16)
            op[(size_t)e * U_N] = hn;                      // global, fire-and-forget
        }
        op += P_N * U_N;
        // ---- stage x(l+2) into A_x[bat][rbuf]; prefetch x(l+4)
        if (l + 2 < L_N) {
            f16x4 v = {(_Float16)xs.x, (_Float16)xs.y, (_Float16)xs.z, (_Float16)xs.w};
            *(f16x4*)&A_x[bat][rbuf][sm][scp] = v;
            if (l + 4 < L_N)
                xs = *(const float4*)(xb + (size_t)((l + 4) * P_N + sm) * F_N + sc);
        }
        BAR();
    };

    for (int l = 0; l < L_N; l += 2) {
        step(l, xsB, P, Q);       // even l consumes xsB (holds x(l+2))
        step(l + 1, xsA, Q, P);   // odd  l consumes xsA
    }
}

extern "C" void kernel_launch(void* const* d_in, const int* in_sizes, int n_in,
                              void* d_out, int out_size, void* d_ws, size_t ws_size,
                              hipStream_t stream) {
    const float* inputs = (const float*)d_in[0];
    const float* kernel = (const float*)d_in[1];
    const float* rker   = (const float*)d_in[2];
    const float* bias   = (const float*)d_in[3];
    float* o = (float*)d_out;
    hipLaunchKernelGGL(skipgru_kernel, dim3(B_N / 2), dim3(NT), 0, stream,
                       inputs, kernel, rker, bias, o);
}

// Round 7
// 320.966 us; speedup vs baseline: 5.3637x; 5.3637x over previous
//
#include <hip/hip_runtime.h>
#include <hip/hip_bf16.h>

// SkipGRU: B=64, T=4096, F=128, U=128, P=16 -> 1024 chains of length 256.
// Phase-split v2:
//   phase1: xm = x@Wk + bias for all B*T rows, written PRE-TRANSPOSED into
//           the exact per-lane layout phase2 reads (fully coalesced both ways).
//   phase2: recurrence, 64 WGs x 8 waves; per step only the h-GEMM
//           (12 MFMAs, depth-2 chains), gates + h in registers, one barrier.
// xmT layout: f16 at ((b*256+l)*12 + p)*512 + q, p = g*4+e (g=z/r/h gate,
// e=row quad), q = consumer thread id (so phase2 loads are stride-1024B
// coalesced; phase1 stores are 128B-contiguous per instruction).
// Fallback = round-4 monolithic kernel (187 us) if workspace too small.

#define B_N 64
#define T_N 4096
#define F_N 128
#define U_N 128
#define P_N 16
#define L_N 256
#define NW 8
#define NT (NW * 64)   // 512 threads

#define XMT_BYTES (64ULL * 256 * 12 * 512 * 2)   // 201326592

typedef _Float16 f16x8 __attribute__((ext_vector_type(8)));
typedef _Float16 f16x4 __attribute__((ext_vector_type(4)));
typedef float f32x4 __attribute__((ext_vector_type(4)));

__device__ __forceinline__ float sigmoidf_(float x) {
    return __builtin_amdgcn_rcpf(1.0f + __expf(-x));
}

// Position of logical k within a fragment-contiguous row:
// row[kt*32 + lg*8 + e] holds k = kt*32 + 16*(e>>2) + 4*lg + (e&3).
__device__ __forceinline__ int fpos(int k) {
    return ((k >> 5) << 5) + (((k >> 2) & 3) << 3) + (((k >> 4) & 1) << 2) + (k & 3);
}

// barrier with LDS-only drain; global loads/stores stay in flight
#define BAR() do { \
    asm volatile("s_waitcnt lgkmcnt(0)" ::: "memory"); \
    __builtin_amdgcn_s_barrier(); \
    __builtin_amdgcn_sched_barrier(0); \
} while (0)

// -------------------------------------------------------------- phase 1 ---
// 2048 WGs x 512 thr; WG g handles rows [g*128, g*128+128) of the B*T row
// space = batch b = g>>5, l-tiles l0..l0+7 with l0 = (g&31)*8.
// Wave ws owns n-tiles ws*3..ws*3+2 (48 cols), weights in registers.
__global__ __launch_bounds__(512, 2) void phase1_kernel(
    const float* __restrict__ xg, const float* __restrict__ Wk,
    const float* __restrict__ bias, _Float16* __restrict__ xmT)
{
    __shared__ __align__(16) _Float16 A[8][16][132];   // frag-contig x rows

    const int tid  = threadIdx.x;
    const int lane = tid & 63;
    const int ws   = tid >> 6;
    const int ln   = lane & 15;
    const int lg   = lane >> 4;
    const int b    = blockIdx.x >> 5;
    const int l0   = (blockIdx.x & 31) * 8;
    const size_t row0 = (size_t)blockIdx.x * 128;

    // weights for this wave's 3 n-tiles (fragment k-map = fpos inverse)
    f16x8 wf[3][4];
    float bc[3];
    #pragma unroll
    for (int j = 0; j < 3; ++j) {
        int col = (ws * 3 + j) * 16 + ln;
        bc[j] = bias[col] + (col < 256 ? bias[384 + col] : 0.0f);
        #pragma unroll
        for (int kt = 0; kt < 4; ++kt)
            #pragma unroll
            for (int e = 0; e < 8; ++e) {
                int k = kt * 32 + ((e >> 2) << 4) + (lg << 2) + (e & 3);
                wf[j][kt][e] = (_Float16)Wk[(size_t)k * 384 + col];
            }
    }

    // stage 128 rows of x into fragment layout
    for (int q = tid; q < 4096; q += 512) {
        int r = q >> 5, c4 = (q & 31) << 2;
        float4 v = *(const float4*)(xg + (row0 + r) * F_N + c4);
        f16x4 h = {(_Float16)v.x, (_Float16)v.y, (_Float16)v.z, (_Float16)v.w};
        *(f16x4*)&A[r >> 4][r & 15][fpos(c4)] = h;
    }
    __syncthreads();

    for (int lt = 0; lt < 8; ++lt) {
        f16x8 af[4];
        #pragma unroll
        for (int kt = 0; kt < 4; ++kt)
            af[kt] = *(const f16x8*)&A[lt][ln][kt * 32 + lg * 8];
        const size_t lblk = ((size_t)b * 256 + (l0 + lt)) * 12;
        #pragma unroll
        for (int j = 0; j < 3; ++j) {
            int nt = ws * 3 + j, g = nt >> 3, c = nt & 7;
            f32x4 acc = {bc[j], bc[j], bc[j], bc[j]};
            #pragma unroll
            for (int kt = 0; kt < 4; ++kt)
                acc = __builtin_amdgcn_mfma_f32_16x16x32_f16(af[kt], wf[j][kt], acc, 0, 0, 0);
            #pragma unroll
            for (int e = 0; e < 4; ++e)
                xmT[(lblk + g * 4 + e) * 512 + c * 64 + lane] = (_Float16)acc[e];
        }
    }
}

// -------------------------------------------------------------- phase 2 ---
struct XmS { _Float16 v[12]; };
#define LOAD_XM(S, l) do { \
    _Pragma("unroll") \
    for (int _p = 0; _p < 12; ++_p) \
        S.v[_p] = xml[((size_t)(l) * 12 + _p) * 512]; \
} while (0)

__global__ __launch_bounds__(NT, 2) void phase2_kernel(
    const float* __restrict__ Wr, const float* __restrict__ bias,
    const _Float16* __restrict__ xmT, float* __restrict__ out)
{
    __shared__ __align__(16) _Float16 A_h[2][16][132];

    const int tid  = threadIdx.x;
    const int lane = tid & 63;
    const int wave = tid >> 6;
    const int ln   = lane & 15;
    const int lg   = lane >> 4;
    const int u    = wave * 16 + ln;
    const int m0   = lg * 4;
    const int b    = blockIdx.x;
    const int hcol = fpos(u);

    const float brh = bias[384 + 256 + u];   // recurrent h-gate bias

    // recurrent weight fragments (z/r/h), k-map = fpos inverse
    f16x8 wzr[4], wrr[4], whr[4];
    #pragma unroll
    for (int kt = 0; kt < 4; ++kt)
        #pragma unroll
        for (int e = 0; e < 8; ++e) {
            int k = kt * 32 + ((e >> 2) << 4) + (lg << 2) + (e & 3);
            const float* wrp = Wr + (size_t)k * 384;
            wzr[kt][e] = (_Float16)wrp[u];
            wrr[kt][e] = (_Float16)wrp[128 + u];
            whr[kt][e] = (_Float16)wrp[256 + u];
        }

    for (int q = tid; q < 16 * 132; q += NT) ((_Float16*)A_h[0])[q] = (_Float16)0;

    const _Float16* xml = xmT + (size_t)b * 256 * 12 * 512 + tid;
    XmS SA, SB;
    LOAD_XM(SA, 0);
    LOAD_XM(SB, 1);

    f32x4 hreg = {0.f, 0.f, 0.f, 0.f};
    float* op = out + ((size_t)b * T_N + m0) * U_N + u;
    __syncthreads();

    auto step = [&](int l, XmS& S) {
        const int rbuf = l & 1, wbuf = (l + 1) & 1;
        f16x8 ahf[4];
        #pragma unroll
        for (int kt = 0; kt < 4; ++kt)
            ahf[kt] = *(const f16x8*)&A_h[rbuf][ln][kt * 32 + lg * 8];
        // xm -> f32 (prefetched 2 steps ago)
        float xh[4];
        f32x4 az0 = {(float)S.v[0], (float)S.v[1], (float)S.v[2], (float)S.v[3]};
        f32x4 ar0 = {(float)S.v[4], (float)S.v[5], (float)S.v[6], (float)S.v[7]};
        #pragma unroll
        for (int e = 0; e < 4; ++e) xh[e] = (float)S.v[8 + e];
        f32x4 ah0 = {brh, brh, brh, brh};
        f32x4 az1 = {0.f, 0.f, 0.f, 0.f}, ar1 = az1, ah1 = az1;
        // 12 MFMAs as 6 chains of depth 2
        az0 = __builtin_amdgcn_mfma_f32_16x16x32_f16(ahf[0], wzr[0], az0, 0, 0, 0);
        ar0 = __builtin_amdgcn_mfma_f32_16x16x32_f16(ahf[0], wrr[0], ar0, 0, 0, 0);
        ah0 = __builtin_amdgcn_mfma_f32_16x16x32_f16(ahf[0], whr[0], ah0, 0, 0, 0);
        az1 = __builtin_amdgcn_mfma_f32_16x16x32_f16(ahf[2], wzr[2], az1, 0, 0, 0);
        ar1 = __builtin_amdgcn_mfma_f32_16x16x32_f16(ahf[2], wrr[2], ar1, 0, 0, 0);
        ah1 = __builtin_amdgcn_mfma_f32_16x16x32_f16(ahf[2], whr[2], ah1, 0, 0, 0);
        az0 = __builtin_amdgcn_mfma_f32_16x16x32_f16(ahf[1], wzr[1], az0, 0, 0, 0);
        ar0 = __builtin_amdgcn_mfma_f32_16x16x32_f16(ahf[1], wrr[1], ar0, 0, 0, 0);
        ah0 = __builtin_amdgcn_mfma_f32_16x16x32_f16(ahf[1], whr[1], ah0, 0, 0, 0);
        az1 = __builtin_amdgcn_mfma_f32_16x16x32_f16(ahf[3], wzr[3], az1, 0, 0, 0);
        ar1 = __builtin_amdgcn_mfma_f32_16x16x32_f16(ahf[3], wrr[3], ar1, 0, 0, 0);
        ah1 = __builtin_amdgcn_mfma_f32_16x16x32_f16(ahf[3], whr[3], ah1, 0, 0, 0);
        // prefetch xm for step l+2 into the same reg set
        if (l + 2 < L_N) LOAD_XM(S, l + 2);
        // gate fully in-register; h never leaves the lane
        #pragma unroll
        for (int e = 0; e < 4; ++e) {
            float z = sigmoidf_(az0[e] + az1[e]);
            float r = sigmoidf_(ar0[e] + ar1[e]);
            float c = fmaxf(0.f, fmaf(r, ah0[e] + ah1[e], xh[e]));
            float hn = fmaf(z, hreg[e] - c, c);
            hreg[e] = hn;
            A_h[wbuf][m0 + e][hcol] = (_Float16)hn;   // transpose write (b16)
            op[(size_t)e * U_N] = hn;                  // global, fire-and-forget
        }
        op += P_N * U_N;
        BAR();
    };

    for (int l = 0; l < L_N; l += 2) {
        step(l, SA);
        step(l + 1, SB);
    }
}

// ---------------------------------------------- fallback (round-4 kernel) --
struct Acc { f32x4 z, r, xh, hh; };

__global__ __launch_bounds__(NT, 2) void skipgru_mono(
    const float* __restrict__ xg, const float* __restrict__ Wk,
    const float* __restrict__ Wr, const float* __restrict__ bias,
    float* __restrict__ out)
{
    __shared__ __align__(16) _Float16 A_x[2][16][132];
    __shared__ __align__(16) _Float16 A_h[2][16][132];

    const int tid  = threadIdx.x;
    const int lane = tid & 63;
    const int wave = tid >> 6;
    const int ln   = lane & 15;
    const int lg   = lane >> 4;
    const int u    = wave * 16 + ln;
    const int m0   = lg * 4;
    const int b    = blockIdx.x;
    const int hcol = fpos(u);

    const float bz  = bias[u]       + bias[384 + u];
    const float br  = bias[128 + u] + bias[384 + 128 + u];
    const float bxh = bias[256 + u];
    const float brh = bias[384 + 256 + u];

    f16x8 wzk[4], wzr[4], wrk[4], wrr[4], whk[4], whr[4];
    #pragma unroll
    for (int kt = 0; kt < 4; ++kt)
        #pragma unroll
        for (int e = 0; e < 8; ++e) {
            int k = kt * 32 + ((e >> 2) << 4) + (lg << 2) + (e & 3);
            const float* wkp = Wk + (size_t)k * 384;
            const float* wrp = Wr + (size_t)k * 384;
            wzk[kt][e] = (_Float16)wkp[u];
            wzr[kt][e] = (_Float16)wrp[u];
            wrk[kt][e] = (_Float16)wkp[128 + u];
            wrr[kt][e] = (_Float16)wrp[128 + u];
            whk[kt][e] = (_Float16)wkp[256 + u];
            whr[kt][e] = (_Float16)wrp[256 + u];
        }

    for (int q = tid; q < 16 * 132; q += NT) ((_Float16*)A_h[0])[q] = (_Float16)0;

    const int sm = tid & 15, sc = (tid >> 4) << 2;
    const int scp = fpos(sc);
    const float* xb = xg + (size_t)b * T_N * F_N;
    {
        float4 x0 = *(const float4*)(xb + (size_t)sm * F_N + sc);
        float4 x1 = *(const float4*)(xb + (size_t)(P_N + sm) * F_N + sc);
        f16x4 v0 = {(_Float16)x0.x, (_Float16)x0.y, (_Float16)x0.z, (_Float16)x0.w};
        f16x4 v1 = {(_Float16)x1.x, (_Float16)x1.y, (_Float16)x1.z, (_Float16)x1.w};
        *(f16x4*)&A_x[0][sm][scp] = v0;
        *(f16x4*)&A_x[1][sm][scp] = v1;
    }
    float4 xsB = *(const float4*)(xb + (size_t)(2 * P_N + sm) * F_N + sc);
    float4 xsA = *(const float4*)(xb + (size_t)(3 * P_N + sm) * F_N + sc);

    f32x4 hreg = {0.f, 0.f, 0.f, 0.f};
    float* op = out + ((size_t)b * T_N + m0) * U_N + u;
    __syncthreads();

    Acc P, Q;
    {
        f16x8 axf[4];
        #pragma unroll
        for (int kt = 0; kt < 4; ++kt)
            axf[kt] = *(const f16x8*)&A_x[0][ln][kt * 32 + lg * 8];
        P.z  = {bz, bz, bz, bz};
        P.r  = {br, br, br, br};
        P.xh = {bxh, bxh, bxh, bxh};
        P.hh = {brh, brh, brh, brh};
        #pragma unroll
        for (int kt = 0; kt < 4; ++kt) {
            P.z  = __builtin_amdgcn_mfma_f32_16x16x32_f16(axf[kt], wzk[kt], P.z, 0, 0, 0);
            P.r  = __builtin_amdgcn_mfma_f32_16x16x32_f16(axf[kt], wrk[kt], P.r, 0, 0, 0);
            P.xh = __builtin_amdgcn_mfma_f32_16x16x32_f16(axf[kt], whk[kt], P.xh, 0, 0, 0);
        }
    }

    auto step = [&](int l, float4& xs, Acc& cur, Acc& nxt) {
        const int rbuf = l & 1, wbuf = (l + 1) & 1;
        f16x8 ahf[4];
        #pragma unroll
        for (int kt = 0; kt < 4; ++kt)
            ahf[kt] = *(const f16x8*)&A_h[rbuf][ln][kt * 32 + lg * 8];
        #pragma unroll
        for (int kt = 0; kt < 4; ++kt) {
            cur.z  = __builtin_amdgcn_mfma_f32_16x16x32_f16(ahf[kt], wzr[kt], cur.z, 0, 0, 0);
            cur.r  = __builtin_amdgcn_mfma_f32_16x16x32_f16(ahf[kt], wrr[kt], cur.r, 0, 0, 0);
            cur.hh = __builtin_amdgcn_mfma_f32_16x16x32_f16(ahf[kt], whr[kt], cur.hh, 0, 0, 0);
        }
        if (l + 1 < L_N) {
            f16x8 axf[4];
            #pragma unroll
            for (int kt = 0; kt < 4; ++kt)
                axf[kt] = *(const f16x8*)&A_x[wbuf][ln][kt * 32 + lg * 8];
            nxt.z  = {bz, bz, bz, bz};
            nxt.r  = {br, br, br, br};
            nxt.xh = {bxh, bxh, bxh, bxh};
            nxt.hh = {brh, brh, brh, brh};
            #pragma unroll
            for (int kt = 0; kt < 4; ++kt) {
                nxt.z  = __builtin_amdgcn_mfma_f32_16x16x32_f16(axf[kt], wzk[kt], nxt.z, 0, 0, 0);
                nxt.r  = __builtin_amdgcn_mfma_f32_16x16x32_f16(axf[kt], wrk[kt], nxt.r, 0, 0, 0);
                nxt.xh = __builtin_amdgcn_mfma_f32_16x16x32_f16(axf[kt], whk[kt], nxt.xh, 0, 0, 0);
            }
        }
        #pragma unroll
        for (int e = 0; e < 4; ++e) {
            float z = sigmoidf_(cur.z[e]);
            float r = sigmoidf_(cur.r[e]);
            float c = fmaxf(0.f, fmaf(r, cur.hh[e], cur.xh[e]));
            float hn = fmaf(z, hreg[e] - c, c);
            hreg[e] = hn;
            A_h[wbuf][m0 + e][hcol] = (_Float16)hn;
            op[(size_t)e * U_N] = hn;
        }
        op += P_N * U_N;
        if (l + 2 < L_N) {
            f16x4 v = {(_Float16)xs.x, (_Float16)xs.y, (_Float16)xs.z, (_Float16)xs.w};
            *(f16x4*)&A_x[rbuf][sm][scp] = v;
            if (l + 4 < L_N)
                xs = *(const float4*)(xb + (size_t)((l + 4) * P_N + sm) * F_N + sc);
        }
        BAR();
    };

    for (int l = 0; l < L_N; l += 2) {
        step(l, xsB, P, Q);
        step(l + 1, xsA, Q, P);
    }
}

extern "C" void kernel_launch(void* const* d_in, const int* in_sizes, int n_in,
                              void* d_out, int out_size, void* d_ws, size_t ws_size,
                              hipStream_t stream) {
    const float* inputs = (const float*)d_in[0];
    const float* kernel = (const float*)d_in[1];
    const float* rker   = (const float*)d_in[2];
    const float* bias   = (const float*)d_in[3];
    float* o = (float*)d_out;

    if (ws_size >= XMT_BYTES) {
        _Float16* xmT = (_Float16*)d_ws;
        hipLaunchKernelGGL(phase1_kernel, dim3(2048), dim3(512), 0, stream,
                           inputs, kernel, bias, xmT);
        hipLaunchKernelGGL(phase2_kernel, dim3(B_N), dim3(NT), 0, stream,
                           rker, bias, xmT, o);
    } else {
        hipLaunchKernelGGL(skipgru_mono, dim3(B_N), dim3(NT), 0, stream,
                           inputs, kernel, rker, bias, o);
    }
}

// Round 9
// 293.144 us; speedup vs baseline: 5.8727x; 1.0949x over previous
//
#include <hip/hip_runtime.h>
#include <hip/hip_bf16.h>

// SkipGRU: B=64, T=4096, F=128, U=128, P=16 -> 1024 chains of length 256.
// Phase-split v3:
//   phase1: xm = x@Wk + bias (z/r pre-scaled by log2e for exp2-sigmoid),
//           waves own u-slices exactly like phase2 -> producer lane ==
//           consumer lane; xmT holds 12 contiguous f16 per (thread, step).
//   phase2: recurrence, 64 WGs x 8 waves; per step: 3x8B xm loads (depth-4
//           prefetch), 4 ds_read_b128, 12 MFMAs, in-register gates via
//           exp2-sigmoid, 4 ds_write_b16, 1 lgkm-only barrier.
// Fallback = round-4 monolithic kernel if workspace too small.

#define B_N 64
#define T_N 4096
#define F_N 128
#define U_N 128
#define P_N 16
#define L_N 256
#define NW 8
#define NT (NW * 64)   // 512 threads

#define LOG2E 1.4426950408889634f
#define XMT_BYTES (64ULL * 256 * 512 * 12 * 2)   // 201326592

typedef _Float16 f16x8 __attribute__((ext_vector_type(8)));
typedef _Float16 f16x4 __attribute__((ext_vector_type(4)));
typedef float f32x4 __attribute__((ext_vector_type(4)));

__device__ __forceinline__ float sigmoid2_(float y) {   // y pre-scaled by log2e
    return __builtin_amdgcn_rcpf(1.0f + __builtin_amdgcn_exp2f(-y));
}

__device__ __forceinline__ float sigmoidf_mono(float x) {
    return __builtin_amdgcn_rcpf(1.0f + __expf(-x));
}

// Position of logical k within a fragment-contiguous row:
// row[kt*32 + lg*8 + e] holds k = kt*32 + 16*(e>>2) + 4*lg + (e&3).
__device__ __forceinline__ int fpos(int k) {
    return ((k >> 5) << 5) + (((k >> 2) & 3) << 3) + (((k >> 4) & 1) << 2) + (k & 3);
}

// barrier with LDS-only drain; global loads/stores stay in flight
#define BAR() do { \
    asm volatile("s_waitcnt lgkmcnt(0)" ::: "memory"); \
    __builtin_amdgcn_s_barrier(); \
    __builtin_amdgcn_sched_barrier(0); \
} while (0)

// -------------------------------------------------------------- phase 1 ---
// 2048 WGs x 512 thr; WG g: batch b = g>>5, l-tiles l0..l0+7, l0=(g&31)*8.
// Wave w owns u-slice w of ALL THREE gates (cols g*128 + w*16 + ln).
__global__ __launch_bounds__(512, 2) void phase1_kernel(
    const float* __restrict__ xg, const float* __restrict__ Wk,
    const float* __restrict__ bias, _Float16* __restrict__ xmT)
{
    __shared__ __align__(16) _Float16 A[8][16][132];   // frag-contig x rows

    const int tid  = threadIdx.x;
    const int lane = tid & 63;
    const int w    = tid >> 6;
    const int ln   = lane & 15;
    const int lg   = lane >> 4;
    const int b    = blockIdx.x >> 5;
    const int l0   = (blockIdx.x & 31) * 8;
    const size_t row0 = (size_t)blockIdx.x * 128;
    const int u    = w * 16 + ln;

    // weight fragments for this wave's u-slice (z/r scaled by log2e)
    f16x8 wzk[4], wrk[4], whk[4];
    #pragma unroll
    for (int kt = 0; kt < 4; ++kt)
        #pragma unroll
        for (int e = 0; e < 8; ++e) {
            int k = kt * 32 + ((e >> 2) << 4) + (lg << 2) + (e & 3);
            const float* wkp = Wk + (size_t)k * 384;
            wzk[kt][e] = (_Float16)(wkp[u] * LOG2E);
            wrk[kt][e] = (_Float16)(wkp[128 + u] * LOG2E);
            whk[kt][e] = (_Float16)wkp[256 + u];
        }
    const float bcz = (bias[u] + bias[384 + u]) * LOG2E;
    const float bcr = (bias[128 + u] + bias[384 + 128 + u]) * LOG2E;
    const float bch = bias[256 + u];

    // stage 128 rows of x into fragment layout
    for (int q = tid; q < 4096; q += 512) {
        int r = q >> 5, c4 = (q & 31) << 2;
        float4 v = *(const float4*)(xg + (row0 + r) * F_N + c4);
        f16x4 h = {(_Float16)v.x, (_Float16)v.y, (_Float16)v.z, (_Float16)v.w};
        *(f16x4*)&A[r >> 4][r & 15][fpos(c4)] = h;
    }
    __syncthreads();

    for (int lt = 0; lt < 8; ++lt) {
        f16x8 af[4];
        #pragma unroll
        for (int kt = 0; kt < 4; ++kt)
            af[kt] = *(const f16x8*)&A[lt][ln][kt * 32 + lg * 8];
        f32x4 az = {bcz, bcz, bcz, bcz};
        f32x4 ar = {bcr, bcr, bcr, bcr};
        f32x4 ah = {bch, bch, bch, bch};
        #pragma unroll
        for (int kt = 0; kt < 4; ++kt) {
            az = __builtin_amdgcn_mfma_f32_16x16x32_f16(af[kt], wzk[kt], az, 0, 0, 0);
            ar = __builtin_amdgcn_mfma_f32_16x16x32_f16(af[kt], wrk[kt], ar, 0, 0, 0);
            ah = __builtin_amdgcn_mfma_f32_16x16x32_f16(af[kt], whk[kt], ah, 0, 0, 0);
        }
        // producer lane == consumer lane: 12 contiguous f16 at tid*12
        _Float16* p = xmT + (((size_t)b * 256 + (l0 + lt)) * 512 + tid) * 12;
        f16x4 vz = {(_Float16)az[0], (_Float16)az[1], (_Float16)az[2], (_Float16)az[3]};
        f16x4 vr = {(_Float16)ar[0], (_Float16)ar[1], (_Float16)ar[2], (_Float16)ar[3]};
        f16x4 vh = {(_Float16)ah[0], (_Float16)ah[1], (_Float16)ah[2], (_Float16)ah[3]};
        *(f16x4*)(p)     = vz;
        *(f16x4*)(p + 4) = vr;
        *(f16x4*)(p + 8) = vh;
    }
}

// -------------------------------------------------------------- phase 2 ---
struct XmS { f16x4 z, r, h; };
#define LOAD_XM(S, l) do { \
    const _Float16* _p = xml + (size_t)(l) * (512 * 12); \
    S.z = *(const f16x4*)(_p); \
    S.r = *(const f16x4*)(_p + 4); \
    S.h = *(const f16x4*)(_p + 8); \
} while (0)

__global__ __launch_bounds__(NT, 2) void phase2_kernel(
    const float* __restrict__ Wr, const float* __restrict__ bias,
    const _Float16* __restrict__ xmT, float* __restrict__ out)
{
    __shared__ __align__(16) _Float16 A_h[2][16][132];

    const int tid  = threadIdx.x;
    const int lane = tid & 63;
    const int wave = tid >> 6;
    const int ln   = lane & 15;
    const int lg   = lane >> 4;
    const int u    = wave * 16 + ln;
    const int m0   = lg * 4;
    const int b    = blockIdx.x;
    const int hcol = fpos(u);

    const float brh = bias[384 + 256 + u];   // recurrent h-gate bias (unscaled)

    // recurrent weight fragments; z/r scaled by log2e for exp2-sigmoid
    f16x8 wzr[4], wrr[4], whr[4];
    #pragma unroll
    for (int kt = 0; kt < 4; ++kt)
        #pragma unroll
        for (int e = 0; e < 8; ++e) {
            int k = kt * 32 + ((e >> 2) << 4) + (lg << 2) + (e & 3);
            const float* wrp = Wr + (size_t)k * 384;
            wzr[kt][e] = (_Float16)(wrp[u] * LOG2E);
            wrr[kt][e] = (_Float16)(wrp[128 + u] * LOG2E);
            whr[kt][e] = (_Float16)wrp[256 + u];
        }

    for (int q = tid; q < 16 * 132; q += NT) ((_Float16*)A_h[0])[q] = (_Float16)0;

    const _Float16* xml = xmT + ((size_t)b * 256 * 512 + tid) * 12;
    XmS S0, S1, S2, S3;
    LOAD_XM(S0, 0);
    LOAD_XM(S1, 1);
    LOAD_XM(S2, 2);
    LOAD_XM(S3, 3);

    f32x4 hreg = {0.f, 0.f, 0.f, 0.f};
    float* op = out + ((size_t)b * T_N + m0) * U_N + u;
    __syncthreads();

    auto step = [&](int l, XmS& S) {
        const int rbuf = l & 1, wbuf = (l + 1) & 1;
        f16x8 ahf[4];
        #pragma unroll
        for (int kt = 0; kt < 4; ++kt)
            ahf[kt] = *(const f16x8*)&A_h[rbuf][ln][kt * 32 + lg * 8];
        // C-init from xm (biases + log2e scaling pre-folded in phase1)
        f32x4 az0 = {(float)S.z[0], (float)S.z[1], (float)S.z[2], (float)S.z[3]};
        f32x4 ar0 = {(float)S.r[0], (float)S.r[1], (float)S.r[2], (float)S.r[3]};
        float xh[4] = {(float)S.h[0], (float)S.h[1], (float)S.h[2], (float)S.h[3]};
        f32x4 ah0 = {brh, brh, brh, brh};
        f32x4 az1 = {0.f, 0.f, 0.f, 0.f}, ar1 = az1, ah1 = az1;
        // 12 MFMAs as 6 chains of depth 2
        az0 = __builtin_amdgcn_mfma_f32_16x16x32_f16(ahf[0], wzr[0], az0, 0, 0, 0);
        ar0 = __builtin_amdgcn_mfma_f32_16x16x32_f16(ahf[0], wrr[0], ar0, 0, 0, 0);
        ah0 = __builtin_amdgcn_mfma_f32_16x16x32_f16(ahf[0], whr[0], ah0, 0, 0, 0);
        az1 = __builtin_amdgcn_mfma_f32_16x16x32_f16(ahf[2], wzr[2], az1, 0, 0, 0);
        ar1 = __builtin_amdgcn_mfma_f32_16x16x32_f16(ahf[2], wrr[2], ar1, 0, 0, 0);
        ah1 = __builtin_amdgcn_mfma_f32_16x16x32_f16(ahf[2], whr[2], ah1, 0, 0, 0);
        az0 = __builtin_amdgcn_mfma_f32_16x16x32_f16(ahf[1], wzr[1], az0, 0, 0, 0);
        ar0 = __builtin_amdgcn_mfma_f32_16x16x32_f16(ahf[1], wrr[1], ar0, 0, 0, 0);
        ah0 = __builtin_amdgcn_mfma_f32_16x16x32_f16(ahf[1], whr[1], ah0, 0, 0, 0);
        az1 = __builtin_amdgcn_mfma_f32_16x16x32_f16(ahf[3], wzr[3], az1, 0, 0, 0);
        ar1 = __builtin_amdgcn_mfma_f32_16x16x32_f16(ahf[3], wrr[3], ar1, 0, 0, 0);
        ah1 = __builtin_amdgcn_mfma_f32_16x16x32_f16(ahf[3], whr[3], ah1, 0, 0, 0);
        // prefetch xm for step l+4 into the same reg set (depth-4 pipeline)
        if (l + 4 < L_N) LOAD_XM(S, l + 4);
        // gate fully in-register; h never leaves the lane
        #pragma unroll
        for (int e = 0; e < 4; ++e) {
            float z = sigmoid2_(az0[e] + az1[e]);
            float r = sigmoid2_(ar0[e] + ar1[e]);
            float c = fmaxf(0.f, fmaf(r, ah0[e] + ah1[e], xh[e]));
            float hn = fmaf(z, hreg[e] - c, c);
            hreg[e] = hn;
            A_h[wbuf][m0 + e][hcol] = (_Float16)hn;   // transpose write (b16)
            op[(size_t)e * U_N] = hn;                  // global, fire-and-forget
        }
        op += P_N * U_N;
        BAR();
    };

    for (int l = 0; l < L_N; l += 4) {
        step(l, S0);
        step(l + 1, S1);
        step(l + 2, S2);
        step(l + 3, S3);
    }
}

// ---------------------------------------------- fallback (round-4 kernel) --
struct Acc { f32x4 z, r, xh, hh; };

__global__ __launch_bounds__(NT, 2) void skipgru_mono(
    const float* __restrict__ xg, const float* __restrict__ Wk,
    const float* __restrict__ Wr, const float* __restrict__ bias,
    float* __restrict__ out)
{
    __shared__ __align__(16) _Float16 A_x[2][16][132];
    __shared__ __align__(16) _Float16 A_h[2][16][132];

    const int tid  = threadIdx.x;
    const int lane = tid & 63;
    const int wave = tid >> 6;
    const int ln   = lane & 15;
    const int lg   = lane >> 4;
    const int u    = wave * 16 + ln;
    const int m0   = lg * 4;
    const int b    = blockIdx.x;
    const int hcol = fpos(u);

    const float bz  = bias[u]       + bias[384 + u];
    const float br  = bias[128 + u] + bias[384 + 128 + u];
    const float bxh = bias[256 + u];
    const float brh = bias[384 + 256 + u];

    f16x8 wzk[4], wzr[4], wrk[4], wrr[4], whk[4], whr[4];
    #pragma unroll
    for (int kt = 0; kt < 4; ++kt)
        #pragma unroll
        for (int e = 0; e < 8; ++e) {
            int k = kt * 32 + ((e >> 2) << 4) + (lg << 2) + (e & 3);
            const float* wkp = Wk + (size_t)k * 384;
            const float* wrp = Wr + (size_t)k * 384;
            wzk[kt][e] = (_Float16)wkp[u];
            wzr[kt][e] = (_Float16)wrp[u];
            wrk[kt][e] = (_Float16)wkp[128 + u];
            wrr[kt][e] = (_Float16)wrp[128 + u];
            whk[kt][e] = (_Float16)wkp[256 + u];
            whr[kt][e] = (_Float16)wrp[256 + u];
        }

    for (int q = tid; q < 16 * 132; q += NT) ((_Float16*)A_h[0])[q] = (_Float16)0;

    const int sm = tid & 15, sc = (tid >> 4) << 2;
    const int scp = fpos(sc);
    const float* xb = xg + (size_t)b * T_N * F_N;
    {
        float4 x0 = *(const float4*)(xb + (size_t)sm * F_N + sc);
        float4 x1 = *(const float4*)(xb + (size_t)(P_N + sm) * F_N + sc);
        f16x4 v0 = {(_Float16)x0.x, (_Float16)x0.y, (_Float16)x0.z, (_Float16)x0.w};
        f16x4 v1 = {(_Float16)x1.x, (_Float16)x1.y, (_Float16)x1.z, (_Float16)x1.w};
        *(f16x4*)&A_x[0][sm][scp] = v0;
        *(f16x4*)&A_x[1][sm][scp] = v1;
    }
    float4 xsB = *(const float4*)(xb + (size_t)(2 * P_N + sm) * F_N + sc);
    float4 xsA = *(const float4*)(xb + (size_t)(3 * P_N + sm) * F_N + sc);

    f32x4 hreg = {0.f, 0.f, 0.f, 0.f};
    float* op = out + ((size_t)b * T_N + m0) * U_N + u;
    __syncthreads();

    Acc P, Q;
    {
        f16x8 axf[4];
        #pragma unroll
        for (int kt = 0; kt < 4; ++kt)
            axf[kt] = *(const f16x8*)&A_x[0][ln][kt * 32 + lg * 8];
        P.z  = {bz, bz, bz, bz};
        P.r  = {br, br, br, br};
        P.xh = {bxh, bxh, bxh, bxh};
        P.hh = {brh, brh, brh, brh};
        #pragma unroll
        for (int kt = 0; kt < 4; ++kt) {
            P.z  = __builtin_amdgcn_mfma_f32_16x16x32_f16(axf[kt], wzk[kt], P.z, 0, 0, 0);
            P.r  = __builtin_amdgcn_mfma_f32_16x16x32_f16(axf[kt], wrk[kt], P.r, 0, 0, 0);
            P.xh = __builtin_amdgcn_mfma_f32_16x16x32_f16(axf[kt], whk[kt], P.xh, 0, 0, 0);
        }
    }

    auto step = [&](int l, float4& xs, Acc& cur, Acc& nxt) {
        const int rbuf = l & 1, wbuf = (l + 1) & 1;
        f16x8 ahf[4];
        #pragma unroll
        for (int kt = 0; kt < 4; ++kt)
            ahf[kt] = *(const f16x8*)&A_h[rbuf][ln][kt * 32 + lg * 8];
        #pragma unroll
        for (int kt = 0; kt < 4; ++kt) {
            cur.z  = __builtin_amdgcn_mfma_f32_16x16x32_f16(ahf[kt], wzr[kt], cur.z, 0, 0, 0);
            cur.r  = __builtin_amdgcn_mfma_f32_16x16x32_f16(ahf[kt], wrr[kt], cur.r, 0, 0, 0);
            cur.hh = __builtin_amdgcn_mfma_f32_16x16x32_f16(ahf[kt], whr[kt], cur.hh, 0, 0, 0);
        }
        if (l + 1 < L_N) {
            f16x8 axf[4];
            #pragma unroll
            for (int kt = 0; kt < 4; ++kt)
                axf[kt] = *(const f16x8*)&A_x[wbuf][ln][kt * 32 + lg * 8];
            nxt.z  = {bz, bz, bz, bz};
            nxt.r  = {br, br, br, br};
            nxt.xh = {bxh, bxh, bxh, bxh};
            nxt.hh = {brh, brh, brh, brh};
            #pragma unroll
            for (int kt = 0; kt < 4; ++kt) {
                nxt.z  = __builtin_amdgcn_mfma_f32_16x16x32_f16(axf[kt], wzk[kt], nxt.z, 0, 0, 0);
                nxt.r  = __builtin_amdgcn_mfma_f32_16x16x32_f16(axf[kt], wrk[kt], nxt.r, 0, 0, 0);
                nxt.xh = __builtin_amdgcn_mfma_f32_16x16x32_f16(axf[kt], whk[kt], nxt.xh, 0, 0, 0);
            }
        }
        #pragma unroll
        for (int e = 0; e < 4; ++e) {
            float z = sigmoidf_mono(cur.z[e]);
            float r = sigmoidf_mono(cur.r[e]);
            float c = fmaxf(0.f, fmaf(r, cur.hh[e], cur.xh[e]));
            float hn = fmaf(z, hreg[e] - c, c);
            hreg[e] = hn;
            A_h[wbuf][m0 + e][hcol] = (_Float16)hn;
            op[(size_t)e * U_N] = hn;
        }
        op += P_N * U_N;
        if (l + 2 < L_N) {
            f16x4 v = {(_Float16)xs.x, (_Float16)xs.y, (_Float16)xs.z, (_Float16)xs.w};
            *(f16x4*)&A_x[rbuf][sm][scp] = v;
            if (l + 4 < L_N)
                xs = *(const float4*)(xb + (size_t)((l + 4) * P_N + sm) * F_N + sc);
        }
        BAR();
    };

    for (int l = 0; l < L_N; l += 2) {
        step(l, xsB, P, Q);
        step(l + 1, xsA, Q, P);
    }
}

extern "C" void kernel_launch(void* const* d_in, const int* in_sizes, int n_in,
                              void* d_out, int out_size, void* d_ws, size_t ws_size,
                              hipStream_t stream) {
    const float* inputs = (const float*)d_in[0];
    const float* kernel = (const float*)d_in[1];
    const float* rker   = (const float*)d_in[2];
    const float* bias   = (const float*)d_in[3];
    float* o = (float*)d_out;

    if (ws_size >= XMT_BYTES) {
        _Float16* xmT = (_Float16*)d_ws;
        hipLaunchKernelGGL(phase1_kernel, dim3(2048), dim3(512), 0, stream,
                           inputs, kernel, bias, xmT);
        hipLaunchKernelGGL(phase2_kernel, dim3(B_N), dim3(NT), 0, stream,
                           rker, bias, xmT, o);
    } else {
        hipLaunchKernelGGL(skipgru_mono, dim3(B_N), dim3(NT), 0, stream,
                           inputs, kernel, rker, bias, o);
    }
}